// Round 9
// baseline (1498.694 us; speedup 1.0000x reference)
//
#include <hip/hip_runtime.h>
#include <math.h>

#define DD 64

__device__ __forceinline__ float silu_f(float x) {
    return x / (1.0f + __expf(-x));
}

__device__ __forceinline__ unsigned f32_to_bf16_rne(float x) {
    unsigned u = __float_as_uint(x);
    unsigned r = ((u >> 16) & 1u) + 0x7fffu;
    return (u + r) >> 16;
}

__device__ __forceinline__ float2 bf2_lo_hi(unsigned u) {
    return make_float2(__uint_as_float(u << 16), __uint_as_float(u & 0xffff0000u));
}

__device__ __forceinline__ void gload_lds4(const float* gsrc, float* lds_base) {
    __builtin_amdgcn_global_load_lds(
        (const __attribute__((address_space(1))) void*)gsrc,
        (__attribute__((address_space(3))) void*)lds_base,
        4, 0, 0);
}

#define RFL(x) __builtin_amdgcn_readfirstlane(x)

// ---------------- Kernel 1a: per-node A,B (scalar), C,D (chiral) + out1 init
__global__ __launch_bounds__(256) void node_transform_kernel(
    const float* __restrict__ ns, const float* __restrict__ nc,
    const float* __restrict__ Ws1, const float* __restrict__ Wc1,
    float* __restrict__ A, float* __restrict__ B,
    float* __restrict__ C, float* __restrict__ Dm,
    float* __restrict__ out1, int N)
{
    __shared__ float w1[128 * 64];
    __shared__ float wc1s[128 * 64];
    __shared__ float xs[4][2][64];
    __shared__ float ys[4][2][64];
    int tid = threadIdx.x;
    for (int i = tid; i < 128 * 64 / 4; i += 256) {
        ((float4*)w1)[i]   = ((const float4*)Ws1)[i];
        ((float4*)wc1s)[i] = ((const float4*)Wc1)[i];
    }
    __syncthreads();
    int wave = tid >> 6, lane = tid & 63;
    for (int nb = blockIdx.x * 8; nb < N; nb += gridDim.x * 8) {
        int n0 = nb + wave * 2;
        #pragma unroll
        for (int s = 0; s < 2; ++s) {
            int n = n0 + s;
            float xv = 0.f, yv = 0.f;
            if (n < N) { xv = ns[(size_t)n * DD + lane]; yv = nc[(size_t)n * DD + lane]; }
            xs[wave][s][lane] = xv;
            ys[wave][s][lane] = yv;
        }
        float aA[2] = {0.f, 0.f}, aB[2] = {0.f, 0.f}, aC[2] = {0.f, 0.f}, aD[2] = {0.f, 0.f};
        for (int k = 0; k < 64; ++k) {
            float wa  = w1[k * 64 + lane];
            float wb  = w1[(64 + k) * 64 + lane];
            float wca = wc1s[k * 64 + lane];
            float wcb = wc1s[(64 + k) * 64 + lane];
            #pragma unroll
            for (int s = 0; s < 2; ++s) {
                float xk = xs[wave][s][k];
                float yk = ys[wave][s][k];
                aA[s] += xk * wa;  aB[s] += xk * wb;
                aC[s] += yk * wca; aD[s] += yk * wcb;
            }
        }
        #pragma unroll
        for (int s = 0; s < 2; ++s) {
            int n = n0 + s;
            if (n < N) {
                A[(size_t)n * DD + lane]  = aA[s];
                B[(size_t)n * DD + lane]  = aB[s];
                C[(size_t)n * DD + lane]  = aC[s];
                Dm[(size_t)n * DD + lane] = aD[s];
                out1[(size_t)n * DD + lane] = ys[wave][s][lane];
            }
        }
    }
}

// ---------------- Kernel 1b: Vv norm -> out0 base, out2 base (nv copy)
__global__ __launch_bounds__(256) void node_vector_kernel(
    const float* __restrict__ ns, const float* __restrict__ nv,
    const float* __restrict__ WV, const float* __restrict__ bV,
    float* __restrict__ out0, float* __restrict__ out2, int N)
{
    __shared__ float wv[64 * 64];
    __shared__ float vs[4][2][3][64];
    int tid = threadIdx.x;
    for (int i = tid; i < 64 * 64 / 4; i += 256)
        ((float4*)wv)[i] = ((const float4*)WV)[i];
    __syncthreads();
    int wave = tid >> 6, lane = tid & 63;
    float bVj = bV[lane];
    for (int nb = blockIdx.x * 8; nb < N; nb += gridDim.x * 8) {
        int n0 = nb + wave * 2;
        #pragma unroll
        for (int s = 0; s < 2; ++s) {
            int n = n0 + s;
            float v0 = 0.f, v1 = 0.f, v2 = 0.f;
            if (n < N) {
                v0 = nv[((size_t)n * 3 + 0) * DD + lane];
                v1 = nv[((size_t)n * 3 + 1) * DD + lane];
                v2 = nv[((size_t)n * 3 + 2) * DD + lane];
            }
            vs[wave][s][0][lane] = v0; vs[wave][s][1][lane] = v1; vs[wave][s][2][lane] = v2;
        }
        float a0[2], a1[2], a2[2];
        #pragma unroll
        for (int s = 0; s < 2; ++s) { a0[s] = bVj; a1[s] = bVj; a2[s] = bVj; }
        for (int k = 0; k < 64; ++k) {
            float w = wv[k * 64 + lane];
            #pragma unroll
            for (int s = 0; s < 2; ++s) {
                a0[s] += vs[wave][s][0][k] * w;
                a1[s] += vs[wave][s][1][k] * w;
                a2[s] += vs[wave][s][2][k] * w;
            }
        }
        #pragma unroll
        for (int s = 0; s < 2; ++s) {
            int n = n0 + s;
            if (n < N) {
                float norm = sqrtf(a0[s] * a0[s] + a1[s] * a1[s] + a2[s] * a2[s]);
                float x = ns[(size_t)n * DD + lane];
                out0[(size_t)n * DD + lane] = x * (1.f + norm);
                out2[((size_t)n * 3 + 0) * DD + lane] = vs[wave][s][0][lane];
                out2[((size_t)n * 3 + 1) * DD + lane] = vs[wave][s][1][lane];
                out2[((size_t)n * 3 + 2) * DD + lane] = vs[wave][s][2][lane];
            }
        }
    }
}

// ---------------- Kernel 2: edges — EPW=2, async LDS staging, occupancy-first
#define EPW 2
__global__ __launch_bounds__(256) void edge_kernel(
    const float* __restrict__ A, const float* __restrict__ B,
    const float* __restrict__ nv, const float* __restrict__ pos,
    const int* __restrict__ eidx,
    const float* __restrict__ bs1, const float* __restrict__ Ws2, const float* __restrict__ bs2,
    float* __restrict__ out0, float* __restrict__ out2, int E)
{
    __shared__ unsigned w2p[32 * 192];       // 24 KiB bf16-packed Ws2
    __shared__ float stA[4][EPW][64];        //  2 KiB (A-row, overwritten with h)
    __shared__ float stB[4][EPW][64];        //  2 KiB
    __shared__ float stV[4][EPW][3][64];     //  6 KiB   -> total 34 KiB
    int tid = threadIdx.x;
    for (int i = tid; i < 32 * 192; i += 256) {
        int kp = i / 192, c = i % 192;
        float a = Ws2[(size_t)(2 * kp) * 192 + c];
        float b = Ws2[(size_t)(2 * kp + 1) * 192 + c];
        w2p[i] = f32_to_bf16_rne(a) | (f32_to_bf16_rne(b) << 16);
    }
    __syncthreads();
    int wave = RFL(tid >> 6);
    int lane = tid & 63;
    float b1  = bs1[lane];
    float b2v = bs2[lane], b2e = bs2[64 + lane], b2s = bs2[128 + lane];

    for (long bb = (long)blockIdx.x * (4 * EPW); bb < E; bb += (long)gridDim.x * (4 * EPW)) {
        long e0b = bb + wave * EPW;
        int i0a[EPW], i1a[EPW];
        #pragma unroll
        for (int e = 0; e < EPW; ++e) {
            long eid = e0b + e;
            int i0 = 0, i1 = 0;
            if (eid < E) { int2 p = ((const int2*)eidx)[eid]; i0 = p.x; i1 = p.y; }
            i0a[e] = RFL(i0);
            i1a[e] = RFL(i1);
        }
        // 10 async row-gathers into LDS (zero VGPR staging)
        #pragma unroll
        for (int e = 0; e < EPW; ++e) {
            gload_lds4(A + ((unsigned)i0a[e] * 64u + lane), &stA[wave][e][0]);
            gload_lds4(B + ((unsigned)i1a[e] * 64u + lane), &stB[wave][e][0]);
            gload_lds4(nv + (((unsigned)i1a[e] * 3u + 0) * 64u + lane), &stV[wave][e][0][0]);
            gload_lds4(nv + (((unsigned)i1a[e] * 3u + 1) * 64u + lane), &stV[wave][e][1][0]);
            gload_lds4(nv + (((unsigned)i1a[e] * 3u + 2) * 64u + lane), &stV[wave][e][2][0]);
        }
        // rel from scalar loads (SGPR indices -> SMEM path, off the vmcnt queue)
        float rx[EPW], ry[EPW], rz[EPW];
        #pragma unroll
        for (int e = 0; e < EPW; ++e) {
            int i0 = i0a[e], i1 = i1a[e];
            rx[e] = pos[(size_t)i1 * 3 + 0] - pos[(size_t)i0 * 3 + 0];
            ry[e] = pos[(size_t)i1 * 3 + 1] - pos[(size_t)i0 * 3 + 1];
            rz[e] = pos[(size_t)i1 * 3 + 2] - pos[(size_t)i0 * 3 + 2];
        }
        asm volatile("s_waitcnt vmcnt(0)" ::: "memory");
        // h phase: in-place over stA
        #pragma unroll
        for (int e = 0; e < EPW; ++e) {
            float h = silu_f(stA[wave][e][lane] + stB[wave][e][lane] + b1);
            stA[wave][e][lane] = h;
        }
        // matvec h @ Ws2 (bf16 weights)
        float agv[EPW], age[EPW], ass[EPW];
        #pragma unroll
        for (int e = 0; e < EPW; ++e) { agv[e] = b2v; age[e] = b2e; ass[e] = b2s; }
        for (int k4 = 0; k4 < 64; k4 += 4) {
            float4 hk[EPW];
            #pragma unroll
            for (int e = 0; e < EPW; ++e) hk[e] = *(const float4*)&stA[wave][e][k4];
            int kp = k4 >> 1;
            float2 w0a = bf2_lo_hi(w2p[kp * 192 + lane]);
            float2 w0b = bf2_lo_hi(w2p[(kp + 1) * 192 + lane]);
            float2 w1a = bf2_lo_hi(w2p[kp * 192 + 64 + lane]);
            float2 w1b = bf2_lo_hi(w2p[(kp + 1) * 192 + 64 + lane]);
            float2 w2a = bf2_lo_hi(w2p[kp * 192 + 128 + lane]);
            float2 w2b = bf2_lo_hi(w2p[(kp + 1) * 192 + 128 + lane]);
            #pragma unroll
            for (int e = 0; e < EPW; ++e) {
                agv[e] += hk[e].x * w0a.x + hk[e].y * w0a.y + hk[e].z * w0b.x + hk[e].w * w0b.y;
                age[e] += hk[e].x * w1a.x + hk[e].y * w1a.y + hk[e].z * w1b.x + hk[e].w * w1b.y;
                ass[e] += hk[e].x * w2a.x + hk[e].y * w2a.y + hk[e].z * w2b.x + hk[e].w * w2b.y;
            }
        }
        // scatter
        #pragma unroll
        for (int e = 0; e < EPW; ++e) {
            long eid = e0b + e;
            if (eid >= E) break;
            int i0 = i0a[e];
            float gv = agv[e], ge = age[e];
            unsafeAtomicAdd(&out0[(unsigned)i0 * 64u + lane], ass[e]);
            unsafeAtomicAdd(&out2[((unsigned)i0 * 3u + 0) * 64u + lane],
                            gv * stV[wave][e][0][lane] + ge * rx[e]);
            unsafeAtomicAdd(&out2[((unsigned)i0 * 3u + 1) * 64u + lane],
                            gv * stV[wave][e][1][lane] + ge * ry[e]);
            unsafeAtomicAdd(&out2[((unsigned)i0 * 3u + 2) * 64u + lane],
                            gv * stV[wave][e][2][lane] + ge * rz[e]);
        }
    }
}

// ---------------- Kernel 3: triplets — round-6 version (async LDS staging)
#define TPW 4
__global__ __launch_bounds__(256) void triplet_kernel(
    const float* __restrict__ C, const float* __restrict__ Dm,
    const float* __restrict__ pos, const int* __restrict__ tidx,
    const float* __restrict__ bc1, const float* __restrict__ Wc2, const float* __restrict__ bc2,
    float* __restrict__ out1, int T)
{
    __shared__ float wT[64 * 64];
    __shared__ float stC[4][TPW][64];
    __shared__ float stD[4][TPW][3][64];
    int tid = threadIdx.x;
    for (int i = tid; i < 64 * 64 / 4; i += 256)
        ((float4*)wT)[i] = ((const float4*)Wc2)[i];
    __syncthreads();
    int wave = RFL(tid >> 6);
    int lane = tid & 63;
    float b1 = bc1[lane];
    float b2 = bc2[lane] * 3.0f;
    for (long bb = (long)blockIdx.x * (4 * TPW); bb < T; bb += (long)gridDim.x * (4 * TPW)) {
        long t0 = bb + wave * TPW;
        int ib[TPW], it1[TPW], it2[TPW], it3[TPW];
        #pragma unroll
        for (int e = 0; e < TPW; ++e) {
            long t = t0 + e;
            int b = 0, t1 = 0, t2 = 0, t3 = 0;
            if (t < T) { int4 q = ((const int4*)tidx)[t]; b = q.x; t1 = q.y; t2 = q.z; t3 = q.w; }
            ib[e]  = RFL(b);
            it1[e] = RFL(t1);
            it2[e] = RFL(t2);
            it3[e] = RFL(t3);
        }
        #pragma unroll
        for (int e = 0; e < TPW; ++e) {
            gload_lds4(C  + (size_t)ib[e]  * DD + lane, &stC[wave][e][0]);
            gload_lds4(Dm + (size_t)it1[e] * DD + lane, &stD[wave][e][0][0]);
            gload_lds4(Dm + (size_t)it2[e] * DD + lane, &stD[wave][e][1][0]);
            gload_lds4(Dm + (size_t)it3[e] * DD + lane, &stD[wave][e][2][0]);
        }
        asm volatile("s_waitcnt vmcnt(0)" ::: "memory");
        float inv[TPW];
        #pragma unroll
        for (int e = 0; e < TPW; ++e) {
            float hb = stC[wave][e][lane] + b1;
            float h = silu_f(hb + stD[wave][e][0][lane])
                    + silu_f(hb + stD[wave][e][1][lane])
                    + silu_f(hb + stD[wave][e][2][lane]);
            stC[wave][e][lane] = h;
            int b = ib[e], t1 = it1[e], t2 = it2[e], t3 = it3[e];
            double pbx = pos[(size_t)b * 3], pby = pos[(size_t)b * 3 + 1], pbz = pos[(size_t)b * 3 + 2];
            double r1x = pbx - pos[(size_t)t1 * 3], r1y = pby - pos[(size_t)t1 * 3 + 1], r1z = pbz - pos[(size_t)t1 * 3 + 2];
            double r2x = pbx - pos[(size_t)t2 * 3], r2y = pby - pos[(size_t)t2 * 3 + 1], r2z = pbz - pos[(size_t)t2 * 3 + 2];
            double r3x = pbx - pos[(size_t)t3 * 3], r3y = pby - pos[(size_t)t3 * 3 + 1], r3z = pbz - pos[(size_t)t3 * 3 + 2];
            double cx = r2y * r3z - r2z * r3y;
            double cy = r2z * r3x - r2x * r3z;
            double cz = r2x * r3y - r2y * r3x;
            double stp = r1x * cx + r1y * cy + r1z * cz;
            inv[e] = (float)(1.0 / (stp + 0.01));
        }
        float acc[TPW];
        #pragma unroll
        for (int e = 0; e < TPW; ++e) acc[e] = 0.f;
        for (int k4 = 0; k4 < 64; k4 += 4) {
            float4 hk[TPW];
            #pragma unroll
            for (int e = 0; e < TPW; ++e) hk[e] = *(const float4*)&stC[wave][e][k4];
            #pragma unroll
            for (int kk = 0; kk < 4; ++kk) {
                float wk = wT[(k4 + kk) * 64 + lane];
                #pragma unroll
                for (int e = 0; e < TPW; ++e) acc[e] += (&hk[e].x)[kk] * wk;
            }
        }
        #pragma unroll
        for (int e = 0; e < TPW; ++e) {
            long t = t0 + e;
            if (t >= T) break;
            unsafeAtomicAdd(&out1[(size_t)ib[e] * DD + lane], (acc[e] + b2) * inv[e]);
        }
    }
}

extern "C" void kernel_launch(void* const* d_in, const int* in_sizes, int n_in,
                              void* d_out, int out_size, void* d_ws, size_t ws_size,
                              hipStream_t stream)
{
    const float* ns  = (const float*)d_in[0];
    const float* nc  = (const float*)d_in[1];
    const float* nv  = (const float*)d_in[2];
    const float* pos = (const float*)d_in[3];
    const int* eidx  = (const int*)d_in[4];
    const int* tidx  = (const int*)d_in[5];
    const float* Ws1 = (const float*)d_in[6];
    const float* bs1 = (const float*)d_in[7];
    const float* Ws2 = (const float*)d_in[8];
    const float* bs2 = (const float*)d_in[9];
    const float* Wc1 = (const float*)d_in[10];
    const float* bc1 = (const float*)d_in[11];
    const float* Wc2 = (const float*)d_in[12];
    const float* bc2 = (const float*)d_in[13];
    const float* WV  = (const float*)d_in[14];
    const float* bV  = (const float*)d_in[15];

    int N = in_sizes[0] / 64;
    int E = in_sizes[4] / 2;
    int T = in_sizes[5] / 4;

    float* out0 = (float*)d_out;
    float* out1 = out0 + (size_t)N * 64;
    float* out2 = out1 + (size_t)N * 64;

    float* A  = (float*)d_ws;
    float* B  = A + (size_t)N * 64;
    float* C  = B + (size_t)N * 64;
    float* Dm = C + (size_t)N * 64;

    node_transform_kernel<<<2048, 256, 0, stream>>>(ns, nc, Ws1, Wc1, A, B, C, Dm, out1, N);
    node_vector_kernel<<<2048, 256, 0, stream>>>(ns, nv, WV, bV, out0, out2, N);
    edge_kernel<<<8192, 256, 0, stream>>>(A, B, nv, pos, eidx, bs1, Ws2, bs2, out0, out2, E);
    triplet_kernel<<<4096, 256, 0, stream>>>(C, Dm, pos, tidx, bc1, Wc2, bc2, out1, T);
}

// Round 10
// 934.392 us; speedup vs baseline: 1.6039x; 1.6039x over previous
//
#include <hip/hip_runtime.h>
#include <math.h>

#define DD 64
typedef unsigned short ushort_t;

__device__ __forceinline__ float silu_f(float x) {
    return x / (1.0f + __expf(-x));
}

__device__ __forceinline__ unsigned f32_to_bf16_rne(float x) {
    unsigned u = __float_as_uint(x);
    unsigned r = ((u >> 16) & 1u) + 0x7fffu;
    return (u + r) >> 16;
}

__device__ __forceinline__ float bf16_to_f32(ushort_t v) {
    return __uint_as_float(((unsigned)v) << 16);
}

__device__ __forceinline__ float2 bf2_lo_hi(unsigned u) {
    return make_float2(__uint_as_float(u << 16), __uint_as_float(u & 0xffff0000u));
}

__device__ __forceinline__ void gload_lds4(const void* gsrc, void* lds_base) {
    __builtin_amdgcn_global_load_lds(
        (const __attribute__((address_space(1))) void*)gsrc,
        (__attribute__((address_space(3))) void*)lds_base,
        4, 0, 0);
}

#define RFL(x) __builtin_amdgcn_readfirstlane(x)

// ---------------- Kernel 1a: per-node A,B (bf16), C,D (f32) + out1 init
__global__ __launch_bounds__(256) void node_transform_kernel(
    const float* __restrict__ ns, const float* __restrict__ nc,
    const float* __restrict__ Ws1, const float* __restrict__ Wc1,
    ushort_t* __restrict__ Abf, ushort_t* __restrict__ Bbf,
    float* __restrict__ C, float* __restrict__ Dm,
    float* __restrict__ out1, int N)
{
    __shared__ float w1[128 * 64];
    __shared__ float wc1s[128 * 64];
    __shared__ float xs[4][2][64];
    __shared__ float ys[4][2][64];
    int tid = threadIdx.x;
    for (int i = tid; i < 128 * 64 / 4; i += 256) {
        ((float4*)w1)[i]   = ((const float4*)Ws1)[i];
        ((float4*)wc1s)[i] = ((const float4*)Wc1)[i];
    }
    __syncthreads();
    int wave = tid >> 6, lane = tid & 63;
    for (int nb = blockIdx.x * 8; nb < N; nb += gridDim.x * 8) {
        int n0 = nb + wave * 2;
        #pragma unroll
        for (int s = 0; s < 2; ++s) {
            int n = n0 + s;
            float xv = 0.f, yv = 0.f;
            if (n < N) { xv = ns[(size_t)n * DD + lane]; yv = nc[(size_t)n * DD + lane]; }
            xs[wave][s][lane] = xv;
            ys[wave][s][lane] = yv;
        }
        float aA[2] = {0.f, 0.f}, aB[2] = {0.f, 0.f}, aC[2] = {0.f, 0.f}, aD[2] = {0.f, 0.f};
        for (int k = 0; k < 64; ++k) {
            float wa  = w1[k * 64 + lane];
            float wb  = w1[(64 + k) * 64 + lane];
            float wca = wc1s[k * 64 + lane];
            float wcb = wc1s[(64 + k) * 64 + lane];
            #pragma unroll
            for (int s = 0; s < 2; ++s) {
                float xk = xs[wave][s][k];
                float yk = ys[wave][s][k];
                aA[s] += xk * wa;  aB[s] += xk * wb;
                aC[s] += yk * wca; aD[s] += yk * wcb;
            }
        }
        #pragma unroll
        for (int s = 0; s < 2; ++s) {
            int n = n0 + s;
            if (n < N) {
                Abf[(size_t)n * DD + lane] = (ushort_t)f32_to_bf16_rne(aA[s]);
                Bbf[(size_t)n * DD + lane] = (ushort_t)f32_to_bf16_rne(aB[s]);
                C[(size_t)n * DD + lane]  = aC[s];
                Dm[(size_t)n * DD + lane] = aD[s];
                out1[(size_t)n * DD + lane] = ys[wave][s][lane];
            }
        }
    }
}

// ---------------- Kernel 1b: Vv norm -> out0 base, out2 base (nv f32) + nvbf (bf16)
__global__ __launch_bounds__(256) void node_vector_kernel(
    const float* __restrict__ ns, const float* __restrict__ nv,
    const float* __restrict__ WV, const float* __restrict__ bV,
    float* __restrict__ out0, float* __restrict__ out2,
    ushort_t* __restrict__ nvbf, int N)
{
    __shared__ float wv[64 * 64];
    __shared__ float vs[4][2][3][64];
    int tid = threadIdx.x;
    for (int i = tid; i < 64 * 64 / 4; i += 256)
        ((float4*)wv)[i] = ((const float4*)WV)[i];
    __syncthreads();
    int wave = tid >> 6, lane = tid & 63;
    float bVj = bV[lane];
    for (int nb = blockIdx.x * 8; nb < N; nb += gridDim.x * 8) {
        int n0 = nb + wave * 2;
        #pragma unroll
        for (int s = 0; s < 2; ++s) {
            int n = n0 + s;
            float v0 = 0.f, v1 = 0.f, v2 = 0.f;
            if (n < N) {
                v0 = nv[((size_t)n * 3 + 0) * DD + lane];
                v1 = nv[((size_t)n * 3 + 1) * DD + lane];
                v2 = nv[((size_t)n * 3 + 2) * DD + lane];
            }
            vs[wave][s][0][lane] = v0; vs[wave][s][1][lane] = v1; vs[wave][s][2][lane] = v2;
        }
        float a0[2], a1[2], a2[2];
        #pragma unroll
        for (int s = 0; s < 2; ++s) { a0[s] = bVj; a1[s] = bVj; a2[s] = bVj; }
        for (int k = 0; k < 64; ++k) {
            float w = wv[k * 64 + lane];
            #pragma unroll
            for (int s = 0; s < 2; ++s) {
                a0[s] += vs[wave][s][0][k] * w;
                a1[s] += vs[wave][s][1][k] * w;
                a2[s] += vs[wave][s][2][k] * w;
            }
        }
        #pragma unroll
        for (int s = 0; s < 2; ++s) {
            int n = n0 + s;
            if (n < N) {
                float norm = sqrtf(a0[s] * a0[s] + a1[s] * a1[s] + a2[s] * a2[s]);
                float x = ns[(size_t)n * DD + lane];
                out0[(size_t)n * DD + lane] = x * (1.f + norm);
                float v0 = vs[wave][s][0][lane], v1 = vs[wave][s][1][lane], v2 = vs[wave][s][2][lane];
                out2[((size_t)n * 3 + 0) * DD + lane] = v0;
                out2[((size_t)n * 3 + 1) * DD + lane] = v1;
                out2[((size_t)n * 3 + 2) * DD + lane] = v2;
                nvbf[((size_t)n * 3 + 0) * DD + lane] = (ushort_t)f32_to_bf16_rne(v0);
                nvbf[((size_t)n * 3 + 1) * DD + lane] = (ushort_t)f32_to_bf16_rne(v1);
                nvbf[((size_t)n * 3 + 2) * DD + lane] = (ushort_t)f32_to_bf16_rne(v2);
            }
        }
    }
}

// ---------------- Kernel 2: edges — bf16 gathers, lane-split packed staging, EPW=8
#define EPW 8
__global__ __launch_bounds__(256) void edge_kernel(
    const ushort_t* __restrict__ Abf, const ushort_t* __restrict__ Bbf,
    const ushort_t* __restrict__ nvbf, const float* __restrict__ pos,
    const int* __restrict__ eidx,
    const float* __restrict__ bs1, const float* __restrict__ Ws2, const float* __restrict__ bs2,
    float* __restrict__ out0, float* __restrict__ out2, int E)
{
    __shared__ unsigned w2p[32 * 192];            // 24 KiB bf16-packed Ws2
    __shared__ ushort_t stAB[4][EPW][128];        //  8 KiB: [0..63]=A row, [64..127]=B row
    __shared__ ushort_t stNV01[4][EPW][128];      //  8 KiB: rows 0,1 of nv[i1]
    __shared__ ushort_t stNV2[4][EPW / 2][128];   //  4 KiB: row 2 of edge pairs
    __shared__ float    stH[4][EPW][64];          //  8 KiB: h (f32)
    int tid = threadIdx.x;
    for (int i = tid; i < 32 * 192; i += 256) {
        int kp = i / 192, c = i % 192;
        float a = Ws2[(size_t)(2 * kp) * 192 + c];
        float b = Ws2[(size_t)(2 * kp + 1) * 192 + c];
        w2p[i] = f32_to_bf16_rne(a) | (f32_to_bf16_rne(b) << 16);
    }
    __syncthreads();
    int wave = RFL(tid >> 6);
    int lane = tid & 63;
    float b1  = bs1[lane];
    float b2v = bs2[lane], b2e = bs2[64 + lane], b2s = bs2[128 + lane];

    long nG = ((long)E + EPW - 1) / EPW;
    for (long g = (long)blockIdx.x * 4 + wave; g < nG; g += (long)gridDim.x * 4) {
        long e0b = g * EPW;
        int i0a[EPW], i1a[EPW];
        #pragma unroll
        for (int e = 0; e < EPW; ++e) {
            long eid = e0b + e; if (eid >= E) eid = E - 1;
            int2 p = ((const int2*)eidx)[eid];
            i0a[e] = RFL(p.x);
            i1a[e] = RFL(p.y);
        }
        // ---- staging: 20 instructions, 5 KB (all bf16)
        #pragma unroll
        for (int e = 0; e < EPW; ++e) {
            // A|B lane-split: lanes 0-31 -> A row of i0, lanes 32-63 -> B row of i1
            const char* srcAB = (lane < 32)
                ? ((const char*)Abf + (size_t)i0a[e] * 128 + lane * 4)
                : ((const char*)Bbf + (size_t)i1a[e] * 128 + (lane - 32) * 4);
            gload_lds4(srcAB, &stAB[wave][e][0]);
            // nv rows 0,1 (256 B contiguous)
            gload_lds4((const char*)nvbf + (size_t)i1a[e] * 384 + lane * 4, &stNV01[wave][e][0]);
        }
        #pragma unroll
        for (int p = 0; p < EPW / 2; ++p) {
            // row 2 of edges 2p / 2p+1, lane-split
            const char* src2 = (lane < 32)
                ? ((const char*)nvbf + (size_t)i1a[2 * p] * 384 + 256 + lane * 4)
                : ((const char*)nvbf + (size_t)i1a[2 * p + 1] * 384 + 256 + (lane - 32) * 4);
            gload_lds4(src2, &stNV2[wave][p][0]);
        }
        asm volatile("s_waitcnt vmcnt(0)" ::: "memory");
        // ---- h phase
        #pragma unroll
        for (int e = 0; e < EPW; ++e) {
            float a = bf16_to_f32(stAB[wave][e][lane]);
            float b = bf16_to_f32(stAB[wave][e][64 + lane]);
            stH[wave][e][lane] = silu_f(a + b + b1);
        }
        // ---- matvec h @ Ws2 (bf16 weights)
        float agv[EPW], age[EPW], ass[EPW];
        #pragma unroll
        for (int e = 0; e < EPW; ++e) { agv[e] = b2v; age[e] = b2e; ass[e] = b2s; }
        for (int k4 = 0; k4 < 64; k4 += 4) {
            int kp = k4 >> 1;
            float2 w0a = bf2_lo_hi(w2p[kp * 192 + lane]);
            float2 w0b = bf2_lo_hi(w2p[(kp + 1) * 192 + lane]);
            float2 w1a = bf2_lo_hi(w2p[kp * 192 + 64 + lane]);
            float2 w1b = bf2_lo_hi(w2p[(kp + 1) * 192 + 64 + lane]);
            float2 w2a = bf2_lo_hi(w2p[kp * 192 + 128 + lane]);
            float2 w2b = bf2_lo_hi(w2p[(kp + 1) * 192 + 128 + lane]);
            #pragma unroll
            for (int e = 0; e < EPW; ++e) {
                float4 hk = *(const float4*)&stH[wave][e][k4];
                agv[e] += hk.x * w0a.x + hk.y * w0a.y + hk.z * w0b.x + hk.w * w0b.y;
                age[e] += hk.x * w1a.x + hk.y * w1a.y + hk.z * w1b.x + hk.w * w1b.y;
                ass[e] += hk.x * w2a.x + hk.y * w2a.y + hk.z * w2b.x + hk.w * w2b.y;
            }
        }
        // ---- scatter
        #pragma unroll
        for (int e = 0; e < EPW; ++e) {
            long eid = e0b + e;
            if (eid >= E) break;
            int i0 = i0a[e], i1 = i1a[e];
            float gv = agv[e], ge = age[e];
            unsafeAtomicAdd(&out0[(unsigned)i0 * 64u + lane], ass[e]);
            float rx = pos[(size_t)i1 * 3 + 0] - pos[(size_t)i0 * 3 + 0];
            float ry = pos[(size_t)i1 * 3 + 1] - pos[(size_t)i0 * 3 + 1];
            float rz = pos[(size_t)i1 * 3 + 2] - pos[(size_t)i0 * 3 + 2];
            float v0 = bf16_to_f32(stNV01[wave][e][lane]);
            float v1 = bf16_to_f32(stNV01[wave][e][64 + lane]);
            float v2 = bf16_to_f32(stNV2[wave][e >> 1][(e & 1) * 64 + lane]);
            unsafeAtomicAdd(&out2[((unsigned)i0 * 3u + 0) * 64u + lane], gv * v0 + ge * rx);
            unsafeAtomicAdd(&out2[((unsigned)i0 * 3u + 1) * 64u + lane], gv * v1 + ge * ry);
            unsafeAtomicAdd(&out2[((unsigned)i0 * 3u + 2) * 64u + lane], gv * v2 + ge * rz);
        }
    }
}

// ---------------- Kernel 3: triplets — round-6 version (async LDS staging, f32)
#define TPW 4
__global__ __launch_bounds__(256) void triplet_kernel(
    const float* __restrict__ C, const float* __restrict__ Dm,
    const float* __restrict__ pos, const int* __restrict__ tidx,
    const float* __restrict__ bc1, const float* __restrict__ Wc2, const float* __restrict__ bc2,
    float* __restrict__ out1, int T)
{
    __shared__ float wT[64 * 64];
    __shared__ float stC[4][TPW][64];
    __shared__ float stD[4][TPW][3][64];
    int tid = threadIdx.x;
    for (int i = tid; i < 64 * 64 / 4; i += 256)
        ((float4*)wT)[i] = ((const float4*)Wc2)[i];
    __syncthreads();
    int wave = RFL(tid >> 6);
    int lane = tid & 63;
    float b1 = bc1[lane];
    float b2 = bc2[lane] * 3.0f;
    for (long bb = (long)blockIdx.x * (4 * TPW); bb < T; bb += (long)gridDim.x * (4 * TPW)) {
        long t0 = bb + wave * TPW;
        int ib[TPW], it1[TPW], it2[TPW], it3[TPW];
        #pragma unroll
        for (int e = 0; e < TPW; ++e) {
            long t = t0 + e;
            int b = 0, t1 = 0, t2 = 0, t3 = 0;
            if (t < T) { int4 q = ((const int4*)tidx)[t]; b = q.x; t1 = q.y; t2 = q.z; t3 = q.w; }
            ib[e]  = RFL(b);
            it1[e] = RFL(t1);
            it2[e] = RFL(t2);
            it3[e] = RFL(t3);
        }
        #pragma unroll
        for (int e = 0; e < TPW; ++e) {
            gload_lds4(C  + (size_t)ib[e]  * DD + lane, &stC[wave][e][0]);
            gload_lds4(Dm + (size_t)it1[e] * DD + lane, &stD[wave][e][0][0]);
            gload_lds4(Dm + (size_t)it2[e] * DD + lane, &stD[wave][e][1][0]);
            gload_lds4(Dm + (size_t)it3[e] * DD + lane, &stD[wave][e][2][0]);
        }
        asm volatile("s_waitcnt vmcnt(0)" ::: "memory");
        float inv[TPW];
        #pragma unroll
        for (int e = 0; e < TPW; ++e) {
            float hb = stC[wave][e][lane] + b1;
            float h = silu_f(hb + stD[wave][e][0][lane])
                    + silu_f(hb + stD[wave][e][1][lane])
                    + silu_f(hb + stD[wave][e][2][lane]);
            stC[wave][e][lane] = h;
            int b = ib[e], t1 = it1[e], t2 = it2[e], t3 = it3[e];
            double pbx = pos[(size_t)b * 3], pby = pos[(size_t)b * 3 + 1], pbz = pos[(size_t)b * 3 + 2];
            double r1x = pbx - pos[(size_t)t1 * 3], r1y = pby - pos[(size_t)t1 * 3 + 1], r1z = pbz - pos[(size_t)t1 * 3 + 2];
            double r2x = pbx - pos[(size_t)t2 * 3], r2y = pby - pos[(size_t)t2 * 3 + 1], r2z = pbz - pos[(size_t)t2 * 3 + 2];
            double r3x = pbx - pos[(size_t)t3 * 3], r3y = pby - pos[(size_t)t3 * 3 + 1], r3z = pbz - pos[(size_t)t3 * 3 + 2];
            double cx = r2y * r3z - r2z * r3y;
            double cy = r2z * r3x - r2x * r3z;
            double cz = r2x * r3y - r2y * r3x;
            double stp = r1x * cx + r1y * cy + r1z * cz;
            inv[e] = (float)(1.0 / (stp + 0.01));
        }
        float acc[TPW];
        #pragma unroll
        for (int e = 0; e < TPW; ++e) acc[e] = 0.f;
        for (int k4 = 0; k4 < 64; k4 += 4) {
            float4 hk[TPW];
            #pragma unroll
            for (int e = 0; e < TPW; ++e) hk[e] = *(const float4*)&stC[wave][e][k4];
            #pragma unroll
            for (int kk = 0; kk < 4; ++kk) {
                float wk = wT[(k4 + kk) * 64 + lane];
                #pragma unroll
                for (int e = 0; e < TPW; ++e) acc[e] += (&hk[e].x)[kk] * wk;
            }
        }
        #pragma unroll
        for (int e = 0; e < TPW; ++e) {
            long t = t0 + e;
            if (t >= T) break;
            unsafeAtomicAdd(&out1[(size_t)ib[e] * DD + lane], (acc[e] + b2) * inv[e]);
        }
    }
}

extern "C" void kernel_launch(void* const* d_in, const int* in_sizes, int n_in,
                              void* d_out, int out_size, void* d_ws, size_t ws_size,
                              hipStream_t stream)
{
    const float* ns  = (const float*)d_in[0];
    const float* nc  = (const float*)d_in[1];
    const float* nv  = (const float*)d_in[2];
    const float* pos = (const float*)d_in[3];
    const int* eidx  = (const int*)d_in[4];
    const int* tidx  = (const int*)d_in[5];
    const float* Ws1 = (const float*)d_in[6];
    const float* bs1 = (const float*)d_in[7];
    const float* Ws2 = (const float*)d_in[8];
    const float* bs2 = (const float*)d_in[9];
    const float* Wc1 = (const float*)d_in[10];
    const float* bc1 = (const float*)d_in[11];
    const float* Wc2 = (const float*)d_in[12];
    const float* bc2 = (const float*)d_in[13];
    const float* WV  = (const float*)d_in[14];
    const float* bV  = (const float*)d_in[15];

    int N = in_sizes[0] / 64;
    int E = in_sizes[4] / 2;
    int T = in_sizes[5] / 4;

    float* out0 = (float*)d_out;
    float* out1 = out0 + (size_t)N * 64;
    float* out2 = out1 + (size_t)N * 64;

    // workspace layout (f32-aligned): C, Dm (f32 N*64 each), then bf16 arrays
    float* C  = (float*)d_ws;
    float* Dm = C + (size_t)N * 64;
    ushort_t* Abf  = (ushort_t*)(Dm + (size_t)N * 64);
    ushort_t* Bbf  = Abf + (size_t)N * 64;
    ushort_t* nvbf = Bbf + (size_t)N * 64;

    node_transform_kernel<<<2048, 256, 0, stream>>>(ns, nc, Ws1, Wc1, Abf, Bbf, C, Dm, out1, N);
    node_vector_kernel<<<2048, 256, 0, stream>>>(ns, nv, WV, bV, out0, out2, nvbf, N);
    edge_kernel<<<4096, 256, 0, stream>>>(Abf, Bbf, nvbf, pos, eidx, bs1, Ws2, bs2, out0, out2, E);
    triplet_kernel<<<4096, 256, 0, stream>>>(C, Dm, pos, tidx, bc1, Wc2, bc2, out1, T);
}

// Round 11
// 914.590 us; speedup vs baseline: 1.6387x; 1.0217x over previous
//
#include <hip/hip_runtime.h>
#include <math.h>

#define DD 64
typedef unsigned short ushort_t;
typedef __attribute__((ext_vector_type(8))) short bf16x8;
typedef __attribute__((ext_vector_type(4))) float f32x4;

__device__ __forceinline__ float silu_f(float x) {
    return x / (1.0f + __expf(-x));
}

__device__ __forceinline__ unsigned f32_to_bf16_rne(float x) {
    unsigned u = __float_as_uint(x);
    unsigned r = ((u >> 16) & 1u) + 0x7fffu;
    return (u + r) >> 16;
}

__device__ __forceinline__ float bf16_to_f32(ushort_t v) {
    return __uint_as_float(((unsigned)v) << 16);
}

__device__ __forceinline__ void gload_lds4(const void* gsrc, void* lds_base) {
    __builtin_amdgcn_global_load_lds(
        (const __attribute__((address_space(1))) void*)gsrc,
        (__attribute__((address_space(3))) void*)lds_base,
        4, 0, 0);
}

#define RFL(x) __builtin_amdgcn_readfirstlane(x)

// ---------------- prep: rel[e] = pos[e1] - pos[e0]  ([E][3] f32, padded)
__global__ __launch_bounds__(256) void rel_kernel(const int* __restrict__ eidx,
                                                  const float* __restrict__ pos,
                                                  float* __restrict__ relg, int E)
{
    int e = blockIdx.x * 256 + threadIdx.x;
    if (e < E) {
        int2 p = ((const int2*)eidx)[e];
        relg[3 * (size_t)e + 0] = pos[(size_t)p.y * 3 + 0] - pos[(size_t)p.x * 3 + 0];
        relg[3 * (size_t)e + 1] = pos[(size_t)p.y * 3 + 1] - pos[(size_t)p.x * 3 + 1];
        relg[3 * (size_t)e + 2] = pos[(size_t)p.y * 3 + 2] - pos[(size_t)p.x * 3 + 2];
    }
}

// ---------------- Kernel 1a: per-node A,B (bf16), C,D (f32) + out1 init
__global__ __launch_bounds__(256) void node_transform_kernel(
    const float* __restrict__ ns, const float* __restrict__ nc,
    const float* __restrict__ Ws1, const float* __restrict__ Wc1,
    ushort_t* __restrict__ Abf, ushort_t* __restrict__ Bbf,
    float* __restrict__ C, float* __restrict__ Dm,
    float* __restrict__ out1, int N)
{
    __shared__ float w1[128 * 64];
    __shared__ float wc1s[128 * 64];
    __shared__ float xs[4][2][64];
    __shared__ float ys[4][2][64];
    int tid = threadIdx.x;
    for (int i = tid; i < 128 * 64 / 4; i += 256) {
        ((float4*)w1)[i]   = ((const float4*)Ws1)[i];
        ((float4*)wc1s)[i] = ((const float4*)Wc1)[i];
    }
    __syncthreads();
    int wave = tid >> 6, lane = tid & 63;
    for (int nb = blockIdx.x * 8; nb < N; nb += gridDim.x * 8) {
        int n0 = nb + wave * 2;
        #pragma unroll
        for (int s = 0; s < 2; ++s) {
            int n = n0 + s;
            float xv = 0.f, yv = 0.f;
            if (n < N) { xv = ns[(size_t)n * DD + lane]; yv = nc[(size_t)n * DD + lane]; }
            xs[wave][s][lane] = xv;
            ys[wave][s][lane] = yv;
        }
        float aA[2] = {0.f, 0.f}, aB[2] = {0.f, 0.f}, aC[2] = {0.f, 0.f}, aD[2] = {0.f, 0.f};
        for (int k = 0; k < 64; ++k) {
            float wa  = w1[k * 64 + lane];
            float wb  = w1[(64 + k) * 64 + lane];
            float wca = wc1s[k * 64 + lane];
            float wcb = wc1s[(64 + k) * 64 + lane];
            #pragma unroll
            for (int s = 0; s < 2; ++s) {
                float xk = xs[wave][s][k];
                float yk = ys[wave][s][k];
                aA[s] += xk * wa;  aB[s] += xk * wb;
                aC[s] += yk * wca; aD[s] += yk * wcb;
            }
        }
        #pragma unroll
        for (int s = 0; s < 2; ++s) {
            int n = n0 + s;
            if (n < N) {
                Abf[(size_t)n * DD + lane] = (ushort_t)f32_to_bf16_rne(aA[s]);
                Bbf[(size_t)n * DD + lane] = (ushort_t)f32_to_bf16_rne(aB[s]);
                C[(size_t)n * DD + lane]  = aC[s];
                Dm[(size_t)n * DD + lane] = aD[s];
                out1[(size_t)n * DD + lane] = ys[wave][s][lane];
            }
        }
    }
}

// ---------------- Kernel 1b: Vv norm -> out0 base, out2 base (nv f32) + nvbf (bf16)
__global__ __launch_bounds__(256) void node_vector_kernel(
    const float* __restrict__ ns, const float* __restrict__ nv,
    const float* __restrict__ WV, const float* __restrict__ bV,
    float* __restrict__ out0, float* __restrict__ out2,
    ushort_t* __restrict__ nvbf, int N)
{
    __shared__ float wv[64 * 64];
    __shared__ float vs[4][2][3][64];
    int tid = threadIdx.x;
    for (int i = tid; i < 64 * 64 / 4; i += 256)
        ((float4*)wv)[i] = ((const float4*)WV)[i];
    __syncthreads();
    int wave = tid >> 6, lane = tid & 63;
    float bVj = bV[lane];
    for (int nb = blockIdx.x * 8; nb < N; nb += gridDim.x * 8) {
        int n0 = nb + wave * 2;
        #pragma unroll
        for (int s = 0; s < 2; ++s) {
            int n = n0 + s;
            float v0 = 0.f, v1 = 0.f, v2 = 0.f;
            if (n < N) {
                v0 = nv[((size_t)n * 3 + 0) * DD + lane];
                v1 = nv[((size_t)n * 3 + 1) * DD + lane];
                v2 = nv[((size_t)n * 3 + 2) * DD + lane];
            }
            vs[wave][s][0][lane] = v0; vs[wave][s][1][lane] = v1; vs[wave][s][2][lane] = v2;
        }
        float a0[2], a1[2], a2[2];
        #pragma unroll
        for (int s = 0; s < 2; ++s) { a0[s] = bVj; a1[s] = bVj; a2[s] = bVj; }
        for (int k = 0; k < 64; ++k) {
            float w = wv[k * 64 + lane];
            #pragma unroll
            for (int s = 0; s < 2; ++s) {
                a0[s] += vs[wave][s][0][k] * w;
                a1[s] += vs[wave][s][1][k] * w;
                a2[s] += vs[wave][s][2][k] * w;
            }
        }
        #pragma unroll
        for (int s = 0; s < 2; ++s) {
            int n = n0 + s;
            if (n < N) {
                float norm = sqrtf(a0[s] * a0[s] + a1[s] * a1[s] + a2[s] * a2[s]);
                float x = ns[(size_t)n * DD + lane];
                out0[(size_t)n * DD + lane] = x * (1.f + norm);
                float v0 = vs[wave][s][0][lane], v1 = vs[wave][s][1][lane], v2 = vs[wave][s][2][lane];
                out2[((size_t)n * 3 + 0) * DD + lane] = v0;
                out2[((size_t)n * 3 + 1) * DD + lane] = v1;
                out2[((size_t)n * 3 + 2) * DD + lane] = v2;
                nvbf[((size_t)n * 3 + 0) * DD + lane] = (ushort_t)f32_to_bf16_rne(v0);
                nvbf[((size_t)n * 3 + 1) * DD + lane] = (ushort_t)f32_to_bf16_rne(v1);
                nvbf[((size_t)n * 3 + 2) * DD + lane] = (ushort_t)f32_to_bf16_rne(v2);
            }
        }
    }
}

// ---------------- Kernel 2: edges — 16 edges/wave, MFMA matvec
#define GEPW 16
__global__ __launch_bounds__(256) void edge_kernel(
    const ushort_t* __restrict__ Abf, const ushort_t* __restrict__ Bbf,
    const ushort_t* __restrict__ nvbf, const float* __restrict__ relg,
    const int* __restrict__ eidx,
    const float* __restrict__ bs1, const float* __restrict__ Ws2, const float* __restrict__ bs2,
    float* __restrict__ out0, float* __restrict__ out2, int E)
{
    // B-fragments of Ws2 in MFMA-ready order: [t][kk][lane][jp] packed bf16x2
    __shared__ unsigned w2frag[12 * 2 * 64 * 4];   // 24 KiB
    __shared__ ushort_t stAB[4][GEPW][128];        // 16 KiB: A|B rows -> h (f32, swizzled)
    __shared__ ushort_t stNV01[4][GEPW][132];      // 16.5 KiB (264B rows: bank spread)
    __shared__ ushort_t stNV2[4][GEPW / 2][132];   // 8.25 KiB
    __shared__ float    relL[4][64];               // 1 KiB: rel rows for the 16-edge group
    int tid = threadIdx.x;
    for (int i = tid; i < 12 * 2 * 64; i += 256) {
        int t  = i >> 7;          // /128
        int kk = (i >> 6) & 1;
        int l  = i & 63;
        int k0 = kk * 32 + (l >> 4) * 8;
        int col = t * 16 + (l & 15);
        #pragma unroll
        for (int jp = 0; jp < 4; ++jp) {
            float a = Ws2[(size_t)(k0 + 2 * jp) * 192 + col];
            float b = Ws2[(size_t)(k0 + 2 * jp + 1) * 192 + col];
            w2frag[i * 4 + jp] = f32_to_bf16_rne(a) | (f32_to_bf16_rne(b) << 16);
        }
    }
    __syncthreads();
    int wave = RFL(tid >> 6);
    int lane = tid & 63;
    float b1 = bs1[lane];
    float b2v_t[4], b2e_t[4], b2s_t[4];
    #pragma unroll
    for (int t = 0; t < 4; ++t) {
        b2v_t[t] = bs2[t * 16 + (lane & 15)];
        b2e_t[t] = bs2[64 + t * 16 + (lane & 15)];
        b2s_t[t] = bs2[128 + t * 16 + (lane & 15)];
    }

    long nG = ((long)E + GEPW - 1) / GEPW;
    for (long g = (long)blockIdx.x * 4 + wave; g < nG; g += (long)gridDim.x * 4) {
        long e0b = g * GEPW;
        int i0a[GEPW], i1a[GEPW];
        #pragma unroll
        for (int e = 0; e < GEPW; ++e) {
            long eid = e0b + e; if (eid >= E) eid = E - 1;
            int2 p = ((const int2*)eidx)[eid];
            i0a[e] = RFL(p.x); i1a[e] = RFL(p.y);
        }
        // ---- staging: 41 async LDS loads, ~10.25 KB in flight
        #pragma unroll
        for (int e = 0; e < GEPW; ++e) {
            const char* srcAB = (lane < 32)
                ? ((const char*)Abf + (size_t)i0a[e] * 128 + lane * 4)
                : ((const char*)Bbf + (size_t)i1a[e] * 128 + (lane - 32) * 4);
            gload_lds4(srcAB, &stAB[wave][e][0]);
            gload_lds4((const char*)nvbf + (size_t)i1a[e] * 384 + lane * 4, &stNV01[wave][e][0]);
        }
        #pragma unroll
        for (int p2 = 0; p2 < GEPW / 2; ++p2) {
            const char* src2 = (lane < 32)
                ? ((const char*)nvbf + (size_t)i1a[2 * p2] * 384 + 256 + lane * 4)
                : ((const char*)nvbf + (size_t)i1a[2 * p2 + 1] * 384 + 256 + (lane - 32) * 4);
            gload_lds4(src2, &stNV2[wave][p2][0]);
        }
        gload_lds4((const char*)relg + e0b * 12 + lane * 4, &relL[wave][0]);
        asm volatile("s_waitcnt vmcnt(0)" ::: "memory");
        __builtin_amdgcn_sched_barrier(0);
        // ---- h phase: read A,B bf16, write h f32 XOR-swizzled over the same row
        #pragma unroll
        for (int e = 0; e < GEPW; ++e) {
            float a = bf16_to_f32(stAB[wave][e][lane]);
            float b = bf16_to_f32(stAB[wave][e][64 + lane]);
            float h = silu_f(a + b + b1);
            *(float*)((char*)&stAB[wave][e][0] + ((lane * 4) ^ ((e & 7) << 5))) = h;
        }
        __builtin_amdgcn_sched_barrier(0);
        // ---- MFMA: G[16x192] = H[16x64] @ Ws2[64x192]
        f32x4 acc[12];
        f32x4 zz = {0.f, 0.f, 0.f, 0.f};
        #pragma unroll
        for (int t = 0; t < 12; ++t) acc[t] = zz;
        int row = lane & 15;
        #pragma unroll
        for (int kk = 0; kk < 2; ++kk) {
            int coff = (kk * 128 + ((lane >> 4) * 32)) ^ ((row & 7) << 5);
            const char* hp = (const char*)&stAB[wave][row][0] + coff;
            float4 lo = *(const float4*)hp;
            float4 hi = *(const float4*)(hp + 16);
            unsigned a0, a1, a2, a3;
            asm("v_cvt_pk_bf16_f32 %0, %1, %2" : "=v"(a0) : "v"(lo.x), "v"(lo.y));
            asm("v_cvt_pk_bf16_f32 %0, %1, %2" : "=v"(a1) : "v"(lo.z), "v"(lo.w));
            asm("v_cvt_pk_bf16_f32 %0, %1, %2" : "=v"(a2) : "v"(hi.x), "v"(hi.y));
            asm("v_cvt_pk_bf16_f32 %0, %1, %2" : "=v"(a3) : "v"(hi.z), "v"(hi.w));
            union { unsigned u[4]; bf16x8 v; } af;
            af.u[0] = a0; af.u[1] = a1; af.u[2] = a2; af.u[3] = a3;
            #pragma unroll
            for (int t = 0; t < 12; ++t) {
                bf16x8 bf = *(const bf16x8*)&w2frag[((t * 2 + kk) * 64 + lane) * 4];
                acc[t] = __builtin_amdgcn_mfma_f32_16x16x32_bf16(af.v, bf, acc[t], 0, 0, 0);
            }
        }
        // ---- scatter straight from fragments: lane holds edges (lane>>4)*4+rg, dims t*16+(lane&15)
        int vi_all = 0;
        #pragma unroll
        for (int e = 0; e < GEPW; ++e) vi_all = (lane == e) ? i0a[e] : vi_all;
        int eLane0 = (lane >> 4) * 4;
        #pragma unroll
        for (int rg = 0; rg < 4; ++rg) {
            int e = eLane0 + rg;
            int i0 = __builtin_amdgcn_ds_bpermute(e * 4, vi_all);
            bool ok = (e0b + e) < E;
            float r0v = relL[wave][e * 3 + 0];
            float r1v = relL[wave][e * 3 + 1];
            float r2v = relL[wave][e * 3 + 2];
            #pragma unroll
            for (int t = 0; t < 4; ++t) {
                int dim = t * 16 + (lane & 15);
                float gv = acc[t][rg]     + b2v_t[t];
                float ge = acc[4 + t][rg] + b2e_t[t];
                float ss = acc[8 + t][rg] + b2s_t[t];
                float v0 = bf16_to_f32(stNV01[wave][e][dim]);
                float v1 = bf16_to_f32(stNV01[wave][e][64 + dim]);
                float v2 = bf16_to_f32(stNV2[wave][e >> 1][(e & 1) * 64 + dim]);
                if (ok) {
                    unsafeAtomicAdd(&out0[(size_t)(unsigned)i0 * 64u + dim], ss);
                    unsafeAtomicAdd(&out2[((size_t)(unsigned)i0 * 3u + 0) * 64u + dim], gv * v0 + ge * r0v);
                    unsafeAtomicAdd(&out2[((size_t)(unsigned)i0 * 3u + 1) * 64u + dim], gv * v1 + ge * r1v);
                    unsafeAtomicAdd(&out2[((size_t)(unsigned)i0 * 3u + 2) * 64u + dim], gv * v2 + ge * r2v);
                }
            }
        }
    }
}

// ---------------- Kernel 3: triplets — round-6 version (async LDS staging, f32)
#define TPW 4
__global__ __launch_bounds__(256) void triplet_kernel(
    const float* __restrict__ C, const float* __restrict__ Dm,
    const float* __restrict__ pos, const int* __restrict__ tidx,
    const float* __restrict__ bc1, const float* __restrict__ Wc2, const float* __restrict__ bc2,
    float* __restrict__ out1, int T)
{
    __shared__ float wT[64 * 64];
    __shared__ float stC[4][TPW][64];
    __shared__ float stD[4][TPW][3][64];
    int tid = threadIdx.x;
    for (int i = tid; i < 64 * 64 / 4; i += 256)
        ((float4*)wT)[i] = ((const float4*)Wc2)[i];
    __syncthreads();
    int wave = RFL(tid >> 6);
    int lane = tid & 63;
    float b1 = bc1[lane];
    float b2 = bc2[lane] * 3.0f;
    for (long bb = (long)blockIdx.x * (4 * TPW); bb < T; bb += (long)gridDim.x * (4 * TPW)) {
        long t0 = bb + wave * TPW;
        int ib[TPW], it1[TPW], it2[TPW], it3[TPW];
        #pragma unroll
        for (int e = 0; e < TPW; ++e) {
            long t = t0 + e;
            int b = 0, t1 = 0, t2 = 0, t3 = 0;
            if (t < T) { int4 q = ((const int4*)tidx)[t]; b = q.x; t1 = q.y; t2 = q.z; t3 = q.w; }
            ib[e]  = RFL(b);
            it1[e] = RFL(t1);
            it2[e] = RFL(t2);
            it3[e] = RFL(t3);
        }
        #pragma unroll
        for (int e = 0; e < TPW; ++e) {
            gload_lds4(C  + (size_t)ib[e]  * DD + lane, &stC[wave][e][0]);
            gload_lds4(Dm + (size_t)it1[e] * DD + lane, &stD[wave][e][0][0]);
            gload_lds4(Dm + (size_t)it2[e] * DD + lane, &stD[wave][e][1][0]);
            gload_lds4(Dm + (size_t)it3[e] * DD + lane, &stD[wave][e][2][0]);
        }
        asm volatile("s_waitcnt vmcnt(0)" ::: "memory");
        float inv[TPW];
        #pragma unroll
        for (int e = 0; e < TPW; ++e) {
            float hb = stC[wave][e][lane] + b1;
            float h = silu_f(hb + stD[wave][e][0][lane])
                    + silu_f(hb + stD[wave][e][1][lane])
                    + silu_f(hb + stD[wave][e][2][lane]);
            stC[wave][e][lane] = h;
            int b = ib[e], t1 = it1[e], t2 = it2[e], t3 = it3[e];
            double pbx = pos[(size_t)b * 3], pby = pos[(size_t)b * 3 + 1], pbz = pos[(size_t)b * 3 + 2];
            double r1x = pbx - pos[(size_t)t1 * 3], r1y = pby - pos[(size_t)t1 * 3 + 1], r1z = pbz - pos[(size_t)t1 * 3 + 2];
            double r2x = pbx - pos[(size_t)t2 * 3], r2y = pby - pos[(size_t)t2 * 3 + 1], r2z = pbz - pos[(size_t)t2 * 3 + 2];
            double r3x = pbx - pos[(size_t)t3 * 3], r3y = pby - pos[(size_t)t3 * 3 + 1], r3z = pbz - pos[(size_t)t3 * 3 + 2];
            double cx = r2y * r3z - r2z * r3y;
            double cy = r2z * r3x - r2x * r3z;
            double cz = r2x * r3y - r2y * r3x;
            double stp = r1x * cx + r1y * cy + r1z * cz;
            inv[e] = (float)(1.0 / (stp + 0.01));
        }
        float acc[TPW];
        #pragma unroll
        for (int e = 0; e < TPW; ++e) acc[e] = 0.f;
        for (int k4 = 0; k4 < 64; k4 += 4) {
            float4 hk[TPW];
            #pragma unroll
            for (int e = 0; e < TPW; ++e) hk[e] = *(const float4*)&stC[wave][e][k4];
            #pragma unroll
            for (int kk = 0; kk < 4; ++kk) {
                float wk = wT[(k4 + kk) * 64 + lane];
                #pragma unroll
                for (int e = 0; e < TPW; ++e) acc[e] += (&hk[e].x)[kk] * wk;
            }
        }
        #pragma unroll
        for (int e = 0; e < TPW; ++e) {
            long t = t0 + e;
            if (t >= T) break;
            unsafeAtomicAdd(&out1[(size_t)ib[e] * DD + lane], (acc[e] + b2) * inv[e]);
        }
    }
}

extern "C" void kernel_launch(void* const* d_in, const int* in_sizes, int n_in,
                              void* d_out, int out_size, void* d_ws, size_t ws_size,
                              hipStream_t stream)
{
    const float* ns  = (const float*)d_in[0];
    const float* nc  = (const float*)d_in[1];
    const float* nv  = (const float*)d_in[2];
    const float* pos = (const float*)d_in[3];
    const int* eidx  = (const int*)d_in[4];
    const int* tidx  = (const int*)d_in[5];
    const float* Ws1 = (const float*)d_in[6];
    const float* bs1 = (const float*)d_in[7];
    const float* Ws2 = (const float*)d_in[8];
    const float* bs2 = (const float*)d_in[9];
    const float* Wc1 = (const float*)d_in[10];
    const float* bc1 = (const float*)d_in[11];
    const float* Wc2 = (const float*)d_in[12];
    const float* bc2 = (const float*)d_in[13];
    const float* WV  = (const float*)d_in[14];
    const float* bV  = (const float*)d_in[15];

    int N = in_sizes[0] / 64;
    int E = in_sizes[4] / 2;
    int T = in_sizes[5] / 4;

    float* out0 = (float*)d_out;
    float* out1 = out0 + (size_t)N * 64;
    float* out2 = out1 + (size_t)N * 64;

    // workspace: C, Dm, relg (f32), then bf16 arrays
    float* C    = (float*)d_ws;
    float* Dm   = C + (size_t)N * 64;
    float* relg = Dm + (size_t)N * 64;                 // E*3 + 64 floats (padded)
    ushort_t* Abf  = (ushort_t*)(relg + (size_t)E * 3 + 64);
    ushort_t* Bbf  = Abf + (size_t)N * 64;
    ushort_t* nvbf = Bbf + (size_t)N * 64;

    rel_kernel<<<(E + 255) / 256, 256, 0, stream>>>(eidx, pos, relg, E);
    node_transform_kernel<<<2048, 256, 0, stream>>>(ns, nc, Ws1, Wc1, Abf, Bbf, C, Dm, out1, N);
    node_vector_kernel<<<2048, 256, 0, stream>>>(ns, nv, WV, bV, out0, out2, nvbf, N);
    edge_kernel<<<4096, 256, 0, stream>>>(Abf, Bbf, nvbf, relg, eidx, bs1, Ws2, bs2, out0, out2, E);
    triplet_kernel<<<4096, 256, 0, stream>>>(C, Dm, pos, tidx, bc1, Wc2, bc2, out1, T);
}